// Round 10
// baseline (207.513 us; speedup 1.0000x reference)
//
#include <hip/hip_runtime.h>
#include <hip/hip_bf16.h>
#include <stdint.h>

#define NB 1024
#define ND 512
#define NC 100000
#define NCT 782          // ceil(NC/128)  (fallback path)
#define NCT2 391         // ceil(NC/256)  (fast path)
#define SSCALE 64.0f
#define SMARG 22.4f      // S*M = 64*0.35

typedef __attribute__((ext_vector_type(8))) short bf16x8;
typedef __attribute__((ext_vector_type(4))) float f32x4;
typedef __attribute__((ext_vector_type(4))) int   i32x4;

__device__ __forceinline__ unsigned int f2bf(float f) {
    union { float f; unsigned int u; } c; c.f = f;
    return (c.u + 0x7fffu + ((c.u >> 16) & 1u)) >> 16;
}

__device__ __forceinline__ float wave_sum(float v) {
    #pragma unroll
    for (int m = 32; m > 0; m >>= 1) v += __shfl_xor(v, m);
    return v;
}

__device__ __forceinline__ float wave_max(float v) {
    #pragma unroll
    for (int m = 32; m > 0; m >>= 1) v = fmaxf(v, __shfl_xor(v, m));
    return v;
}

// async global->LDS, 16B per lane; LDS dest is wave-uniform base + lane*16
__device__ __forceinline__ void load_lds16(const void* g, void* l) {
    auto gp = reinterpret_cast<const __attribute__((address_space(1))) void*>(
        (uintptr_t)g);
    auto lp = reinterpret_cast<__attribute__((address_space(3))) void*>(
        (uint32_t)(uintptr_t)l);
    __builtin_amdgcn_global_load_lds(gp, lp, 16, 0, 0);
}

// ---------------- fast path: int8 quantized normalize ----------------
__global__ void norm_input_i8_k(const float* __restrict__ x,
                                unsigned char* __restrict__ xq,
                                float* __restrict__ isx) {
    int lane = threadIdx.x & 63;
    int row = blockIdx.x * 4 + (threadIdx.x >> 6);
    const float* xr = x + (size_t)row * ND + lane * 8;
    float4 v0 = ((const float4*)xr)[0];
    float4 v1 = ((const float4*)xr)[1];
    float ss = v0.x*v0.x + v0.y*v0.y + v0.z*v0.z + v0.w*v0.w
             + v1.x*v1.x + v1.y*v1.y + v1.z*v1.z + v1.w*v1.w;
    ss = wave_sum(ss);
    float inv = 1.0f / fmaxf(sqrtf(ss), 1e-12f);
    float f[8] = {v0.x*inv, v0.y*inv, v0.z*inv, v0.w*inv,
                  v1.x*inv, v1.y*inv, v1.z*inv, v1.w*inv};
    float ma = 0.0f;
    #pragma unroll
    for (int j = 0; j < 8; ++j) ma = fmaxf(ma, fabsf(f[j]));
    ma = wave_max(ma);
    ma = fmaxf(ma, 1e-12f);
    float s = 127.0f / ma;
    int q[8];
    #pragma unroll
    for (int j = 0; j < 8; ++j) q[j] = (int)rintf(f[j] * s);
    uint2 o;
    o.x = (q[0]&255) | ((q[1]&255)<<8) | ((q[2]&255)<<16) | ((unsigned)(q[3]&255)<<24);
    o.y = (q[4]&255) | ((q[5]&255)<<8) | ((q[6]&255)<<16) | ((unsigned)(q[7]&255)<<24);
    *(uint2*)(xq + (size_t)row * ND + lane * 8) = o;
    if (lane == 0) isx[row] = ma * (1.0f / 127.0f);
}

__global__ void conv_weight_i8_k(const float* __restrict__ w,
                                 unsigned char* __restrict__ wq,
                                 float* __restrict__ isw) {
    int lane = threadIdx.x & 63;
    int row = blockIdx.x * 4 + (threadIdx.x >> 6);
    const float* wr = w + (size_t)row * ND + lane * 8;
    float4 v0 = ((const float4*)wr)[0];
    float4 v1 = ((const float4*)wr)[1];
    float ss = v0.x*v0.x + v0.y*v0.y + v0.z*v0.z + v0.w*v0.w
             + v1.x*v1.x + v1.y*v1.y + v1.z*v1.z + v1.w*v1.w;
    ss = wave_sum(ss);
    float inv = 1.0f / fmaxf(sqrtf(ss), 1e-12f);
    float f[8] = {v0.x*inv, v0.y*inv, v0.z*inv, v0.w*inv,
                  v1.x*inv, v1.y*inv, v1.z*inv, v1.w*inv};
    float ma = 0.0f;
    #pragma unroll
    for (int j = 0; j < 8; ++j) ma = fmaxf(ma, fabsf(f[j]));
    ma = wave_max(ma);
    ma = fmaxf(ma, 1e-12f);
    float s = 127.0f / ma;
    int q[8];
    #pragma unroll
    for (int j = 0; j < 8; ++j) q[j] = (int)rintf(f[j] * s);
    uint2 o;
    o.x = (q[0]&255) | ((q[1]&255)<<8) | ((q[2]&255)<<16) | ((unsigned)(q[3]&255)<<24);
    o.y = (q[4]&255) | ((q[5]&255)<<8) | ((q[6]&255)<<16) | ((unsigned)(q[7]&255)<<24);
    *(uint2*)(wq + (size_t)row * ND + lane * 8) = o;
    if (lane == 0) isw[row] = ma * (1.0f / 127.0f);
}

// ---------------- 256x256 int8 GEMM: A via LDS, W direct global->VGPR --------
// 512 threads = 8 waves (2M x 4N), per-wave 128x64, BK=64 (i8).
// A LDS layout [4 K-chunks][256 rows][16B]: DMA dest linear per thread,
// quarter-wave ds_read = 256B contiguous (2-way, conflict-free).
// W frags loaded straight to registers (L2-resident, prefetched 1 tile ahead,
// compiler-pipelined with partial vmcnt waits -- no barrier coupling).
__global__ __launch_bounds__(512, 2) void gemm_i8_k(
    const unsigned char* __restrict__ xq, const unsigned char* __restrict__ wq,
    const float* __restrict__ isx, const float* __restrict__ isw,
    const int* __restrict__ label,
    float* __restrict__ partial, float* __restrict__ tgt) {

    __shared__ __align__(16) char Ab[2][16384];
    __shared__ float rowsum[4][256];
    __shared__ int labs[256];
    __shared__ float isxs[256];
    __shared__ float isws[256];

    // bijective XCD swizzle: nwg = 1564 = 8*195 + 4 (q=195, r=4; m204 formula)
    const int orig = blockIdx.x + (blockIdx.y << 2);
    const int xcd = orig & 7, idx = orig >> 3;
    const int wg = (xcd < 4 ? xcd * 196 : 784 + (xcd - 4) * 195) + idx;
    const int bx = wg & 3;          // B-tile (0..3)
    const int by = wg >> 2;         // C-tile (0..390)

    const int tid = threadIdx.x;
    const int lane = tid & 63;
    const int wid  = tid >> 6;
    const int brow0 = bx * 256;
    const int crow0 = by * 256;

    if (tid < 256) {
        labs[tid] = label[brow0 + tid];
        isxs[tid] = isx[brow0 + tid];
        int c = crow0 + tid;
        isws[tid] = (c < NC) ? isw[c] : 1.0f;
    }

    // A staging: 1024 16B-chunks per tile, 2 per thread.
    // load i, thread tid -> LDS dest = i*8192 + tid*16  == page c*4096 + r*16
    // with c = 2i + (tid>>8), r = tid&255. Source = xq[(brow0+r)*ND + c*16 +kt*64]
    const int sr = tid & 255;
    const int sc0 = tid >> 8;
    const unsigned char* gA0 = xq + (size_t)(brow0 + sr) * ND + sc0 * 16;
    const unsigned char* gA1 = gA0 + 32;           // chunks 2,3
    const int d0 = tid * 16;
    const int d1 = d0 + 8192;

    const int wr = wid >> 2, wc = wid & 3; // 2M x 4N wave grid
    const int l15 = lane & 15, l4 = lane >> 4;

    // W direct pointers: row = crow0 + wc*64 + n*16 + l15, bytes l4*16 (+kt*64)
    const unsigned char* gW[4];
    #pragma unroll
    for (int n = 0; n < 4; ++n) {
        int br = crow0 + wc * 64 + n * 16 + l15;
        if (br >= NC) br = NC - 1;         // clamp: cols >= NC masked in epilogue
        gW[n] = wq + (size_t)br * ND + l4 * 16;
    }

    i32x4 acc[8][4];
    #pragma unroll
    for (int i = 0; i < 8; ++i)
        #pragma unroll
        for (int j = 0; j < 4; ++j) acc[i][j] = (i32x4){0, 0, 0, 0};

    // prologue: stage A tile 0, load W tile 0
    load_lds16(gA0, &Ab[0][d0]);
    load_lds16(gA1, &Ab[0][d1]);
    i32x4 wcur[4], wnxt[4];
    #pragma unroll
    for (int n = 0; n < 4; ++n) wcur[n] = *(const i32x4*)(gW[n]);
    __syncthreads();   // vmcnt(0) drain: A tile 0 + W tile 0 landed

    // 8 K-tiles of 64 (i8)
    #pragma unroll
    for (int t = 0; t < 8; ++t) {
        // prefetch next tile: A DMA + W global->reg (drained at end-of-tile sync)
        if (t < 7) {
            const int ko = (t + 1) * 64;
            load_lds16(gA0 + ko, &Ab[(t + 1) & 1][d0]);
            load_lds16(gA1 + ko, &Ab[(t + 1) & 1][d1]);
            #pragma unroll
            for (int n = 0; n < 4; ++n) wnxt[n] = *(const i32x4*)(gW[n] + ko);
        }
        const char* cb = Ab[t & 1];
        const int abase = l4 * 4096 + (wr * 128 + l15) * 16;
        i32x4 afr[8];
        #pragma unroll
        for (int m = 0; m < 8; ++m)
            afr[m] = *(const i32x4*)(cb + abase + m * 256);
        __builtin_amdgcn_s_setprio(1);
        #pragma unroll
        for (int m = 0; m < 8; ++m)
            #pragma unroll
            for (int n = 0; n < 4; ++n)
                acc[m][n] = __builtin_amdgcn_mfma_i32_16x16x64_i8(
                    afr[m], wcur[n], acc[m][n], 0, 0, 0);
        __builtin_amdgcn_s_setprio(0);
        #pragma unroll
        for (int n = 0; n < 4; ++n) wcur[n] = wnxt[n];
        if (t < 7) __syncthreads();   // next A tile + W regs landed; buf swap safe
    }

    // epilogue: cos = idot*isx*isw; z = 64*cos (- 22.4 at label); e = exp(z-64)
    float rs[8][4];
    #pragma unroll
    for (int mi = 0; mi < 8; ++mi)
        #pragma unroll
        for (int r = 0; r < 4; ++r) rs[mi][r] = 0.0f;

    #pragma unroll
    for (int mi = 0; mi < 8; ++mi) {
        #pragma unroll
        for (int ni = 0; ni < 4; ++ni) {
            int ci = wc * 64 + ni * 16 + l15;
            int gc = crow0 + ci;
            float iw = isws[ci] * SSCALE;
            i32x4 av = acc[mi][ni];
            #pragma unroll
            for (int r = 0; r < 4; ++r) {
                int tr = wr * 128 + mi * 16 + l4 * 4 + r;
                float z = (float)av[r] * isxs[tr] * iw;
                if (gc == labs[tr]) {
                    z -= SMARG;
                    tgt[brow0 + tr] = z;               // unique writer per row
                }
                float e = (gc < NC) ? __expf(z - 64.0f) : 0.0f;
                rs[mi][r] += e;
            }
        }
    }
    #pragma unroll
    for (int mi = 0; mi < 8; ++mi)
        #pragma unroll
        for (int r = 0; r < 4; ++r) {
            float v = rs[mi][r];
            v += __shfl_xor(v, 1); v += __shfl_xor(v, 2);
            v += __shfl_xor(v, 4); v += __shfl_xor(v, 8);
            rs[mi][r] = v;
        }
    __syncthreads();   // all ds_reads of Ab done block-wide before rowsum reuse
    if (l15 == 0) {
        #pragma unroll
        for (int mi = 0; mi < 8; ++mi)
            #pragma unroll
            for (int r = 0; r < 4; ++r)
                rowsum[wc][wr * 128 + mi * 16 + l4 * 4 + r] = rs[mi][r];
    }
    __syncthreads();
    if (tid < 256)
        partial[(size_t)by * NB + brow0 + tid] =
            rowsum[0][tid] + rowsum[1][tid] + rowsum[2][tid] + rowsum[3][tid];
}

// ---------------- fallback path (bf16, round-1 structure; passes) ----------------
__global__ void norm_input_k(const float* __restrict__ x, unsigned short* __restrict__ xn) {
    int lane = threadIdx.x & 63;
    int row = blockIdx.x * 4 + (threadIdx.x >> 6);
    const float* xr = x + row * ND + lane * 8;
    float4 v0 = ((const float4*)xr)[0];
    float4 v1 = ((const float4*)xr)[1];
    float ss = v0.x*v0.x + v0.y*v0.y + v0.z*v0.z + v0.w*v0.w
             + v1.x*v1.x + v1.y*v1.y + v1.z*v1.z + v1.w*v1.w;
    ss = wave_sum(ss);
    float inv = 1.0f / fmaxf(sqrtf(ss), 1e-12f);
    int4 o;
    o.x = f2bf(v0.x*inv) | (f2bf(v0.y*inv) << 16);
    o.y = f2bf(v0.z*inv) | (f2bf(v0.w*inv) << 16);
    o.z = f2bf(v1.x*inv) | (f2bf(v1.y*inv) << 16);
    o.w = f2bf(v1.z*inv) | (f2bf(v1.w*inv) << 16);
    *(int4*)(xn + row * ND + lane * 8) = o;
}

__global__ void norm_weight_k(const float* __restrict__ w, float* __restrict__ invw) {
    int lane = threadIdx.x & 63;
    int row = blockIdx.x * 4 + (threadIdx.x >> 6);
    if (row >= NC) return;
    const float* wr = w + (size_t)row * ND + lane * 8;
    float4 v0 = ((const float4*)wr)[0];
    float4 v1 = ((const float4*)wr)[1];
    float ss = v0.x*v0.x + v0.y*v0.y + v0.z*v0.z + v0.w*v0.w
             + v1.x*v1.x + v1.y*v1.y + v1.z*v1.z + v1.w*v1.w;
    ss = wave_sum(ss);
    if (lane == 0) invw[row] = 1.0f / fmaxf(sqrtf(ss), 1e-12f);
}

__global__ __launch_bounds__(256) void gemm_fb_k(
    const unsigned short* __restrict__ xn, const float* __restrict__ w,
    const float* __restrict__ invw, const int* __restrict__ label,
    float* __restrict__ partial, float* __restrict__ tgt) {

    __shared__ __align__(16) char As[16384];
    __shared__ __align__(16) char Ws[16384];
    __shared__ float rowsum[2][128];
    __shared__ int labs[128];

    const int tid = threadIdx.x;
    const int brow0 = blockIdx.x * 128;
    const int crow0 = blockIdx.y * 128;

    if (tid < 128) labs[tid] = label[brow0 + tid];

    int arow[4], ac16[4];
    float wiv[4];
    bool  wval[4];
    #pragma unroll
    for (int i = 0; i < 4; ++i) {
        int idx = tid + i * 256;
        arow[i] = idx >> 3; ac16[i] = idx & 7;
        int grow = crow0 + (idx >> 3);
        wval[i] = grow < NC;
        wiv[i]  = wval[i] ? invw[grow] : 0.0f;
    }

    const int lane = tid & 63;
    const int wid  = tid >> 6;
    const int wr = wid >> 1, wc = wid & 1;
    const int l15 = lane & 15, l4 = lane >> 4;

    f32x4 acc[4][4];
    #pragma unroll
    for (int i = 0; i < 4; ++i)
        #pragma unroll
        for (int j = 0; j < 4; ++j) acc[i][j] = (f32x4){0.f, 0.f, 0.f, 0.f};

    for (int ks = 0; ks < 8; ++ks) {
        const int kbase = ks * 64;
        __syncthreads();
        #pragma unroll
        for (int i = 0; i < 4; ++i) {
            int row = arow[i], c16 = ac16[i];
            int4 v = *(const int4*)(xn + (brow0 + row) * ND + kbase + c16 * 8);
            *(int4*)(As + row * 128 + ((c16 * 16) ^ ((row & 7) << 4))) = v;
        }
        #pragma unroll
        for (int i = 0; i < 4; ++i) {
            int row = arow[i], c8 = ac16[i];
            float4 w0 = {0.f,0.f,0.f,0.f}, w1 = {0.f,0.f,0.f,0.f};
            if (wval[i]) {
                const float* wp = w + (size_t)(crow0 + row) * ND + kbase + c8 * 8;
                w0 = ((const float4*)wp)[0];
                w1 = ((const float4*)wp)[1];
            }
            float iv = wiv[i];
            int4 o;
            o.x = f2bf(w0.x*iv) | (f2bf(w0.y*iv) << 16);
            o.y = f2bf(w0.z*iv) | (f2bf(w0.w*iv) << 16);
            o.z = f2bf(w1.x*iv) | (f2bf(w1.y*iv) << 16);
            o.w = f2bf(w1.z*iv) | (f2bf(w1.w*iv) << 16);
            *(int4*)(Ws + row * 128 + ((c8 * 16) ^ ((row & 7) << 4))) = o;
        }
        __syncthreads();
        #pragma unroll
        for (int k32 = 0; k32 < 2; ++k32) {
            const int kb = k32 * 64 + l4 * 16;
            bf16x8 a[4], b[4];
            #pragma unroll
            for (int mi = 0; mi < 4; ++mi) {
                int ar = wr * 64 + mi * 16 + l15;
                a[mi] = *(const bf16x8*)(As + ar * 128 + (kb ^ ((ar & 7) << 4)));
            }
            #pragma unroll
            for (int ni = 0; ni < 4; ++ni) {
                int br = wc * 64 + ni * 16 + l15;
                b[ni] = *(const bf16x8*)(Ws + br * 128 + (kb ^ ((br & 7) << 4)));
            }
            #pragma unroll
            for (int mi = 0; mi < 4; ++mi)
                #pragma unroll
                for (int ni = 0; ni < 4; ++ni)
                    acc[mi][ni] = __builtin_amdgcn_mfma_f32_16x16x32_bf16(
                        a[mi], b[ni], acc[mi][ni], 0, 0, 0);
        }
    }

    float rs[4][4];
    #pragma unroll
    for (int mi = 0; mi < 4; ++mi)
        #pragma unroll
        for (int r = 0; r < 4; ++r) rs[mi][r] = 0.0f;

    #pragma unroll
    for (int mi = 0; mi < 4; ++mi) {
        #pragma unroll
        for (int ni = 0; ni < 4; ++ni) {
            int gc = crow0 + wc * 64 + ni * 16 + l15;
            f32x4 av = acc[mi][ni];
            #pragma unroll
            for (int r = 0; r < 4; ++r) {
                int tr = wr * 64 + mi * 16 + l4 * 4 + r;
                float z = SSCALE * av[r];
                if (gc == labs[tr]) {
                    z -= SMARG;
                    tgt[brow0 + tr] = z;
                }
                float e = (gc < NC) ? __expf(z - 64.0f) : 0.0f;
                rs[mi][r] += e;
            }
        }
    }
    #pragma unroll
    for (int mi = 0; mi < 4; ++mi)
        #pragma unroll
        for (int r = 0; r < 4; ++r) {
            float v = rs[mi][r];
            v += __shfl_xor(v, 1); v += __shfl_xor(v, 2);
            v += __shfl_xor(v, 4); v += __shfl_xor(v, 8);
            rs[mi][r] = v;
        }
    if (l15 == 0) {
        #pragma unroll
        for (int mi = 0; mi < 4; ++mi)
            #pragma unroll
            for (int r = 0; r < 4; ++r)
                rowsum[wc][wr * 64 + mi * 16 + l4 * 4 + r] = rs[mi][r];
    }
    __syncthreads();
    if (tid < 128)
        partial[(size_t)blockIdx.y * NB + brow0 + tid] = rowsum[0][tid] + rowsum[1][tid];
}

// per-row: sum partials, lse = 64 + log(sum), loss_b = lse - tgt[b]
__global__ void row_lse_k(const float* __restrict__ partial, const float* __restrict__ tgt,
                          float* __restrict__ lossb, int nt) {
    int b = blockIdx.x;
    float s = 0.0f;
    for (int i = threadIdx.x; i < nt; i += 256)
        s += partial[(size_t)i * NB + b];
    s = wave_sum(s);
    __shared__ float wsum[4];
    if ((threadIdx.x & 63) == 0) wsum[threadIdx.x >> 6] = s;
    __syncthreads();
    if (threadIdx.x == 0)
        lossb[b] = 64.0f + logf(wsum[0] + wsum[1] + wsum[2] + wsum[3]) - tgt[b];
}

__global__ void mean_k(const float* __restrict__ lossb, float* __restrict__ out) {
    float s = 0.0f;
    for (int i = threadIdx.x; i < NB; i += 256) s += lossb[i];
    s = wave_sum(s);
    __shared__ float wsum[4];
    if ((threadIdx.x & 63) == 0) wsum[threadIdx.x >> 6] = s;
    __syncthreads();
    if (threadIdx.x == 0)
        out[0] = (wsum[0] + wsum[1] + wsum[2] + wsum[3]) * (1.0f / (float)NB);
}

extern "C" void kernel_launch(void* const* d_in, const int* in_sizes, int n_in,
                              void* d_out, int out_size, void* d_ws, size_t ws_size,
                              hipStream_t stream) {
    const float* x     = (const float*)d_in[0];
    const int*   label = (const int*)d_in[1];
    const float* w     = (const float*)d_in[2];
    float* out = (float*)d_out;
    char* ws = (char*)d_ws;

    // fast-path workspace layout (16B aligned)
    const size_t WQ_B   = (size_t)NC * ND;        // 51,200,000
    const size_t ISW_B  = 400000;                 // NC*4
    const size_t XQ_B   = (size_t)NB * ND;        // 524,288
    const size_t ISX_B  = 4096;
    const size_t PART2  = (size_t)NCT2 * NB * 4;  // 1,601,536
    const size_t FAST_REQ = WQ_B + ISW_B + XQ_B + ISX_B + PART2 + 8192;

    if (ws_size >= FAST_REQ) {
        unsigned char* wq      = (unsigned char*)(ws);
        float*         iswv    = (float*)(ws + WQ_B);
        unsigned char* xq      = (unsigned char*)(ws + WQ_B + ISW_B);
        float*         isxv    = (float*)(ws + WQ_B + ISW_B + XQ_B);
        float*         partial = (float*)(ws + WQ_B + ISW_B + XQ_B + ISX_B);
        float*         tgt     = (float*)(ws + WQ_B + ISW_B + XQ_B + ISX_B + PART2);
        float*         lossb   = (float*)(ws + WQ_B + ISW_B + XQ_B + ISX_B + PART2 + 4096);

        norm_input_i8_k <<<NB / 4, 256, 0, stream>>>(x, xq, isxv);
        conv_weight_i8_k<<<NC / 4, 256, 0, stream>>>(w, wq, iswv);
        dim3 grid(4, NCT2);
        gemm_i8_k<<<grid, 512, 0, stream>>>(xq, wq, isxv, iswv, label, partial, tgt);
        row_lse_k<<<NB, 256, 0, stream>>>(partial, tgt, lossb, NCT2);
        mean_k<<<1, 256, 0, stream>>>(lossb, out);
    } else {
        float*          invw    = (float*)(ws);
        unsigned short* xn      = (unsigned short*)(ws + 400384);
        float*          partial = (float*)(ws + 400384 + 1048576);
        float*          tgt     = (float*)(ws + 400384 + 1048576 + 3203072);
        float*          lossb   = (float*)(ws + 400384 + 1048576 + 3203072 + 4096);

        norm_input_k <<<NB / 4, 256, 0, stream>>>(x, xn);
        norm_weight_k<<<NC / 4, 256, 0, stream>>>(w, invw);
        dim3 grid(8, NCT);
        gemm_fb_k<<<grid, 256, 0, stream>>>(xn, w, invw, label, partial, tgt);
        row_lse_k<<<NB, 256, 0, stream>>>(partial, tgt, lossb, NCT);
        mean_k<<<1, 256, 0, stream>>>(lossb, out);
    }
}

// Round 11
// 163.693 us; speedup vs baseline: 1.2677x; 1.2677x over previous
//
#include <hip/hip_runtime.h>
#include <hip/hip_bf16.h>
#include <stdint.h>

#define NB 1024
#define ND 512
#define NC 100000
#define NCT 782          // ceil(NC/128)  (fallback path)
#define NCT2 391         // ceil(NC/256)  (fast path)
#define SSCALE 64.0f
#define SMARG 22.4f      // S*M = 64*0.35

typedef __attribute__((ext_vector_type(8))) short bf16x8;
typedef __attribute__((ext_vector_type(4))) float f32x4;
typedef __attribute__((ext_vector_type(4))) int   i32x4;

__device__ __forceinline__ unsigned int f2bf(float f) {
    union { float f; unsigned int u; } c; c.f = f;
    return (c.u + 0x7fffu + ((c.u >> 16) & 1u)) >> 16;
}

__device__ __forceinline__ float wave_sum(float v) {
    #pragma unroll
    for (int m = 32; m > 0; m >>= 1) v += __shfl_xor(v, m);
    return v;
}

__device__ __forceinline__ float wave_max(float v) {
    #pragma unroll
    for (int m = 32; m > 0; m >>= 1) v = fmaxf(v, __shfl_xor(v, m));
    return v;
}

// async global->LDS, 16B per lane; LDS dest is wave-uniform base + lane*16
__device__ __forceinline__ void load_lds16(const void* g, void* l) {
    auto gp = reinterpret_cast<const __attribute__((address_space(1))) void*>(
        (uintptr_t)g);
    auto lp = reinterpret_cast<__attribute__((address_space(3))) void*>(
        (uint32_t)(uintptr_t)l);
    __builtin_amdgcn_global_load_lds(gp, lp, 16, 0, 0);
}

// ---------------- fast path: int8 quantized normalize ----------------
// one wave per row: L2-normalize, per-row max-abs, symmetric int8 quant.
// iscale[row] = maxabs/127 so cos = idot * iscale_x[r] * iscale_w[c].
__global__ void norm_input_i8_k(const float* __restrict__ x,
                                unsigned char* __restrict__ xq,
                                float* __restrict__ isx) {
    int lane = threadIdx.x & 63;
    int row = blockIdx.x * 4 + (threadIdx.x >> 6);
    const float* xr = x + (size_t)row * ND + lane * 8;
    float4 v0 = ((const float4*)xr)[0];
    float4 v1 = ((const float4*)xr)[1];
    float ss = v0.x*v0.x + v0.y*v0.y + v0.z*v0.z + v0.w*v0.w
             + v1.x*v1.x + v1.y*v1.y + v1.z*v1.z + v1.w*v1.w;
    ss = wave_sum(ss);
    float inv = 1.0f / fmaxf(sqrtf(ss), 1e-12f);
    float f[8] = {v0.x*inv, v0.y*inv, v0.z*inv, v0.w*inv,
                  v1.x*inv, v1.y*inv, v1.z*inv, v1.w*inv};
    float ma = 0.0f;
    #pragma unroll
    for (int j = 0; j < 8; ++j) ma = fmaxf(ma, fabsf(f[j]));
    ma = wave_max(ma);
    ma = fmaxf(ma, 1e-12f);
    float s = 127.0f / ma;
    int q[8];
    #pragma unroll
    for (int j = 0; j < 8; ++j) q[j] = (int)rintf(f[j] * s);
    uint2 o;
    o.x = (q[0]&255) | ((q[1]&255)<<8) | ((q[2]&255)<<16) | ((unsigned)(q[3]&255)<<24);
    o.y = (q[4]&255) | ((q[5]&255)<<8) | ((q[6]&255)<<16) | ((unsigned)(q[7]&255)<<24);
    *(uint2*)(xq + (size_t)row * ND + lane * 8) = o;
    if (lane == 0) isx[row] = ma * (1.0f / 127.0f);
}

__global__ void conv_weight_i8_k(const float* __restrict__ w,
                                 unsigned char* __restrict__ wq,
                                 float* __restrict__ isw) {
    int lane = threadIdx.x & 63;
    int row = blockIdx.x * 4 + (threadIdx.x >> 6);
    const float* wr = w + (size_t)row * ND + lane * 8;
    float4 v0 = ((const float4*)wr)[0];
    float4 v1 = ((const float4*)wr)[1];
    float ss = v0.x*v0.x + v0.y*v0.y + v0.z*v0.z + v0.w*v0.w
             + v1.x*v1.x + v1.y*v1.y + v1.z*v1.z + v1.w*v1.w;
    ss = wave_sum(ss);
    float inv = 1.0f / fmaxf(sqrtf(ss), 1e-12f);
    float f[8] = {v0.x*inv, v0.y*inv, v0.z*inv, v0.w*inv,
                  v1.x*inv, v1.y*inv, v1.z*inv, v1.w*inv};
    float ma = 0.0f;
    #pragma unroll
    for (int j = 0; j < 8; ++j) ma = fmaxf(ma, fabsf(f[j]));
    ma = wave_max(ma);
    ma = fmaxf(ma, 1e-12f);
    float s = 127.0f / ma;
    int q[8];
    #pragma unroll
    for (int j = 0; j < 8; ++j) q[j] = (int)rintf(f[j] * s);
    uint2 o;
    o.x = (q[0]&255) | ((q[1]&255)<<8) | ((q[2]&255)<<16) | ((unsigned)(q[3]&255)<<24);
    o.y = (q[4]&255) | ((q[5]&255)<<8) | ((q[6]&255)<<16) | ((unsigned)(q[7]&255)<<24);
    *(uint2*)(wq + (size_t)row * ND + lane * 8) = o;
    if (lane == 0) isw[row] = ma * (1.0f / 127.0f);
}

// ---------------- 256x256 int8 GEMM (mfma_i32_16x16x64_i8, 2x bf16 rate) -----
// 512 threads = 8 waves (2M x 4N), per-wave 128x64, BK=64 (i8), dbuf LDS 64KB.
// LDS row r (128B) = A-row r K-bytes (4 chunks) | W-row r K-bytes (4 chunks),
// chunk ^= (r&7) swizzle (proven 0-conflict). Round-5 simple schedule:
// 1 syncthreads/tile; stage t+1 between frag reads; setprio MFMA.
// [round 10 lesson: W must stay on the coalesced DMA path -- per-lane
//  global->VGPR W loads are row-strided gathers and regressed 119->168 us]
__global__ __launch_bounds__(512, 2) void gemm_i8_k(
    const unsigned char* __restrict__ xq, const unsigned char* __restrict__ wq,
    const float* __restrict__ isx, const float* __restrict__ isw,
    const int* __restrict__ label,
    float* __restrict__ partial, float* __restrict__ tgt) {

    __shared__ __align__(16) char Tb[2][32768];
    __shared__ float rowsum[4][256];
    __shared__ int labs[256];
    __shared__ float isxs[256];
    __shared__ float isws[256];

    // bijective XCD swizzle: nwg = 1564 = 8*195 + 4 (q=195, r=4; m204 formula)
    const int orig = blockIdx.x + (blockIdx.y << 2);
    const int xcd = orig & 7, idx = orig >> 3;
    const int wg = (xcd < 4 ? xcd * 196 : 784 + (xcd - 4) * 195) + idx;
    const int bx = wg & 3;          // B-tile (0..3)
    const int by = wg >> 2;         // C-tile (0..390)

    const int tid = threadIdx.x;
    const int lane = tid & 63;
    const int wid  = tid >> 6;
    const int brow0 = bx * 256;
    const int crow0 = by * 256;

    if (tid < 256) {
        labs[tid] = label[brow0 + tid];
        isxs[tid] = isx[brow0 + tid];
        int c = crow0 + tid;
        isws[tid] = (c < NC) ? isw[c] : 1.0f;
    }

    // staging: 2048 16B-chunks per tile (A 1024 + W 1024 interleaved), 4/thread.
    // chunk cidx: row = cidx>>3, slot s = cidx&7; logical l = s ^ (r&7);
    // l<4 -> A K-chunk l ; l>=4 -> W K-chunk l-4. LDS dest linear.
    const unsigned char* gsrc[4];
    int ldst[4];
    #pragma unroll
    for (int i = 0; i < 4; ++i) {
        int cidx = wid * 256 + i * 64 + lane;
        int r = cidx >> 3, s = cidx & 7;
        int l = s ^ (r & 7);
        if (l < 4) {
            gsrc[i] = xq + (size_t)(brow0 + r) * ND + l * 16;
        } else {
            int wrow = crow0 + r;
            if (wrow >= NC) wrow = NC - 1;   // clamp: cols >= NC masked in epilogue
            gsrc[i] = wq + (size_t)wrow * ND + (l - 4) * 16;
        }
        ldst[i] = cidx * 16;
    }

    const int wr = wid >> 2, wc = wid & 3; // 2M x 4N wave grid
    const int l15 = lane & 15, l4 = lane >> 4;

    i32x4 acc[8][4];
    #pragma unroll
    for (int i = 0; i < 8; ++i)
        #pragma unroll
        for (int j = 0; j < 4; ++j) acc[i][j] = (i32x4){0, 0, 0, 0};

    // prologue: stage K-tile 0 into buffer 0
    #pragma unroll
    for (int i = 0; i < 4; ++i) load_lds16(gsrc[i], &Tb[0][ldst[i]]);

    // 8 K-tiles of 64 (i8)
    #pragma unroll
    for (int t = 0; t < 8; ++t) {
        __syncthreads();   // buf[t&1] staged (loads ~1 tile of MFMA old)
        const char* cb = Tb[t & 1];
        i32x4 a0[4], a1[4], bfr[4];
        // B frags (one per N-subtile; lane: col=l15, K-chunk l4 of W 64B half)
        #pragma unroll
        for (int n = 0; n < 4; ++n) {
            int br = wc * 64 + n * 16 + l15;
            bfr[n] = *(const i32x4*)(cb + br * 128 + (((4 + l4) << 4) ^ ((br & 7) << 4)));
        }
        // A frags, M-half 0
        #pragma unroll
        for (int m = 0; m < 4; ++m) {
            int ar = wr * 128 + m * 16 + l15;
            a0[m] = *(const i32x4*)(cb + ar * 128 + ((l4 << 4) ^ ((ar & 7) << 4)));
        }
        // stage K-tile t+1 into other buffer
        if (t < 7) {
            char* nb = Tb[(t + 1) & 1];
            #pragma unroll
            for (int i = 0; i < 4; ++i)
                load_lds16(gsrc[i] + (t + 1) * 64, &nb[ldst[i]]);
        }
        // A frags, M-half 1
        #pragma unroll
        for (int m = 0; m < 4; ++m) {
            int ar = wr * 128 + (4 + m) * 16 + l15;
            a1[m] = *(const i32x4*)(cb + ar * 128 + ((l4 << 4) ^ ((ar & 7) << 4)));
        }
        __builtin_amdgcn_s_setprio(1);
        #pragma unroll
        for (int m = 0; m < 4; ++m)
            #pragma unroll
            for (int n = 0; n < 4; ++n)
                acc[m][n] = __builtin_amdgcn_mfma_i32_16x16x64_i8(
                    a0[m], bfr[n], acc[m][n], 0, 0, 0);
        __builtin_amdgcn_s_setprio(0);
        __builtin_amdgcn_s_setprio(1);
        #pragma unroll
        for (int m = 0; m < 4; ++m)
            #pragma unroll
            for (int n = 0; n < 4; ++n)
                acc[4 + m][n] = __builtin_amdgcn_mfma_i32_16x16x64_i8(
                    a1[m], bfr[n], acc[4 + m][n], 0, 0, 0);
        __builtin_amdgcn_s_setprio(0);
    }

    // epilogue: cos = idot*isx*isw; z = 64*cos (- 22.4 at label); e = exp(z-64)
    float rs[8][4];
    #pragma unroll
    for (int mi = 0; mi < 8; ++mi)
        #pragma unroll
        for (int r = 0; r < 4; ++r) rs[mi][r] = 0.0f;

    #pragma unroll
    for (int mi = 0; mi < 8; ++mi) {
        #pragma unroll
        for (int ni = 0; ni < 4; ++ni) {
            int ci = wc * 64 + ni * 16 + l15;
            int gc = crow0 + ci;
            float iw = isws[ci] * SSCALE;
            i32x4 av = acc[mi][ni];
            #pragma unroll
            for (int r = 0; r < 4; ++r) {
                int tr = wr * 128 + mi * 16 + l4 * 4 + r;
                float z = (float)av[r] * isxs[tr] * iw;
                if (gc == labs[tr]) {
                    z -= SMARG;
                    tgt[brow0 + tr] = z;               // unique writer per row
                }
                float e = (gc < NC) ? __expf(z - 64.0f) : 0.0f;
                rs[mi][r] += e;
            }
        }
    }
    #pragma unroll
    for (int mi = 0; mi < 8; ++mi)
        #pragma unroll
        for (int r = 0; r < 4; ++r) {
            float v = rs[mi][r];
            v += __shfl_xor(v, 1); v += __shfl_xor(v, 2);
            v += __shfl_xor(v, 4); v += __shfl_xor(v, 8);
            rs[mi][r] = v;
        }
    if (l15 == 0) {
        #pragma unroll
        for (int mi = 0; mi < 8; ++mi)
            #pragma unroll
            for (int r = 0; r < 4; ++r)
                rowsum[wc][wr * 128 + mi * 16 + l4 * 4 + r] = rs[mi][r];
    }
    __syncthreads();
    if (tid < 256)
        partial[(size_t)by * NB + brow0 + tid] =
            rowsum[0][tid] + rowsum[1][tid] + rowsum[2][tid] + rowsum[3][tid];
}

// ---------------- fallback path (bf16, round-1 structure; passes) ----------------
__global__ void norm_input_k(const float* __restrict__ x, unsigned short* __restrict__ xn) {
    int lane = threadIdx.x & 63;
    int row = blockIdx.x * 4 + (threadIdx.x >> 6);
    const float* xr = x + row * ND + lane * 8;
    float4 v0 = ((const float4*)xr)[0];
    float4 v1 = ((const float4*)xr)[1];
    float ss = v0.x*v0.x + v0.y*v0.y + v0.z*v0.z + v0.w*v0.w
             + v1.x*v1.x + v1.y*v1.y + v1.z*v1.z + v1.w*v1.w;
    ss = wave_sum(ss);
    float inv = 1.0f / fmaxf(sqrtf(ss), 1e-12f);
    int4 o;
    o.x = f2bf(v0.x*inv) | (f2bf(v0.y*inv) << 16);
    o.y = f2bf(v0.z*inv) | (f2bf(v0.w*inv) << 16);
    o.z = f2bf(v1.x*inv) | (f2bf(v1.y*inv) << 16);
    o.w = f2bf(v1.z*inv) | (f2bf(v1.w*inv) << 16);
    *(int4*)(xn + row * ND + lane * 8) = o;
}

__global__ void norm_weight_k(const float* __restrict__ w, float* __restrict__ invw) {
    int lane = threadIdx.x & 63;
    int row = blockIdx.x * 4 + (threadIdx.x >> 6);
    if (row >= NC) return;
    const float* wr = w + (size_t)row * ND + lane * 8;
    float4 v0 = ((const float4*)wr)[0];
    float4 v1 = ((const float4*)wr)[1];
    float ss = v0.x*v0.x + v0.y*v0.y + v0.z*v0.z + v0.w*v0.w
             + v1.x*v1.x + v1.y*v1.y + v1.z*v1.z + v1.w*v1.w;
    ss = wave_sum(ss);
    if (lane == 0) invw[row] = 1.0f / fmaxf(sqrtf(ss), 1e-12f);
}

__global__ __launch_bounds__(256) void gemm_fb_k(
    const unsigned short* __restrict__ xn, const float* __restrict__ w,
    const float* __restrict__ invw, const int* __restrict__ label,
    float* __restrict__ partial, float* __restrict__ tgt) {

    __shared__ __align__(16) char As[16384];
    __shared__ __align__(16) char Ws[16384];
    __shared__ float rowsum[2][128];
    __shared__ int labs[128];

    const int tid = threadIdx.x;
    const int brow0 = blockIdx.x * 128;
    const int crow0 = blockIdx.y * 128;

    if (tid < 128) labs[tid] = label[brow0 + tid];

    int arow[4], ac16[4];
    float wiv[4];
    bool  wval[4];
    #pragma unroll
    for (int i = 0; i < 4; ++i) {
        int idx = tid + i * 256;
        arow[i] = idx >> 3; ac16[i] = idx & 7;
        int grow = crow0 + (idx >> 3);
        wval[i] = grow < NC;
        wiv[i]  = wval[i] ? invw[grow] : 0.0f;
    }

    const int lane = tid & 63;
    const int wid  = tid >> 6;
    const int wr = wid >> 1, wc = wid & 1;
    const int l15 = lane & 15, l4 = lane >> 4;

    f32x4 acc[4][4];
    #pragma unroll
    for (int i = 0; i < 4; ++i)
        #pragma unroll
        for (int j = 0; j < 4; ++j) acc[i][j] = (f32x4){0.f, 0.f, 0.f, 0.f};

    for (int ks = 0; ks < 8; ++ks) {
        const int kbase = ks * 64;
        __syncthreads();
        #pragma unroll
        for (int i = 0; i < 4; ++i) {
            int row = arow[i], c16 = ac16[i];
            int4 v = *(const int4*)(xn + (brow0 + row) * ND + kbase + c16 * 8);
            *(int4*)(As + row * 128 + ((c16 * 16) ^ ((row & 7) << 4))) = v;
        }
        #pragma unroll
        for (int i = 0; i < 4; ++i) {
            int row = arow[i], c8 = ac16[i];
            float4 w0 = {0.f,0.f,0.f,0.f}, w1 = {0.f,0.f,0.f,0.f};
            if (wval[i]) {
                const float* wp = w + (size_t)(crow0 + row) * ND + kbase + c8 * 8;
                w0 = ((const float4*)wp)[0];
                w1 = ((const float4*)wp)[1];
            }
            float iv = wiv[i];
            int4 o;
            o.x = f2bf(w0.x*iv) | (f2bf(w0.y*iv) << 16);
            o.y = f2bf(w0.z*iv) | (f2bf(w0.w*iv) << 16);
            o.z = f2bf(w1.x*iv) | (f2bf(w1.y*iv) << 16);
            o.w = f2bf(w1.z*iv) | (f2bf(w1.w*iv) << 16);
            *(int4*)(Ws + row * 128 + ((c8 * 16) ^ ((row & 7) << 4))) = o;
        }
        __syncthreads();
        #pragma unroll
        for (int k32 = 0; k32 < 2; ++k32) {
            const int kb = k32 * 64 + l4 * 16;
            bf16x8 a[4], b[4];
            #pragma unroll
            for (int mi = 0; mi < 4; ++mi) {
                int ar = wr * 64 + mi * 16 + l15;
                a[mi] = *(const bf16x8*)(As + ar * 128 + (kb ^ ((ar & 7) << 4)));
            }
            #pragma unroll
            for (int ni = 0; ni < 4; ++ni) {
                int br = wc * 64 + ni * 16 + l15;
                b[ni] = *(const bf16x8*)(Ws + br * 128 + (kb ^ ((br & 7) << 4)));
            }
            #pragma unroll
            for (int mi = 0; mi < 4; ++mi)
                #pragma unroll
                for (int ni = 0; ni < 4; ++ni)
                    acc[mi][ni] = __builtin_amdgcn_mfma_f32_16x16x32_bf16(
                        a[mi], b[ni], acc[mi][ni], 0, 0, 0);
        }
    }

    float rs[4][4];
    #pragma unroll
    for (int mi = 0; mi < 4; ++mi)
        #pragma unroll
        for (int r = 0; r < 4; ++r) rs[mi][r] = 0.0f;

    #pragma unroll
    for (int mi = 0; mi < 4; ++mi) {
        #pragma unroll
        for (int ni = 0; ni < 4; ++ni) {
            int gc = crow0 + wc * 64 + ni * 16 + l15;
            f32x4 av = acc[mi][ni];
            #pragma unroll
            for (int r = 0; r < 4; ++r) {
                int tr = wr * 64 + mi * 16 + l4 * 4 + r;
                float z = SSCALE * av[r];
                if (gc == labs[tr]) {
                    z -= SMARG;
                    tgt[brow0 + tr] = z;
                }
                float e = (gc < NC) ? __expf(z - 64.0f) : 0.0f;
                rs[mi][r] += e;
            }
        }
    }
    #pragma unroll
    for (int mi = 0; mi < 4; ++mi)
        #pragma unroll
        for (int r = 0; r < 4; ++r) {
            float v = rs[mi][r];
            v += __shfl_xor(v, 1); v += __shfl_xor(v, 2);
            v += __shfl_xor(v, 4); v += __shfl_xor(v, 8);
            rs[mi][r] = v;
        }
    if (l15 == 0) {
        #pragma unroll
        for (int mi = 0; mi < 4; ++mi)
            #pragma unroll
            for (int r = 0; r < 4; ++r)
                rowsum[wc][wr * 64 + mi * 16 + l4 * 4 + r] = rs[mi][r];
    }
    __syncthreads();
    if (tid < 128)
        partial[(size_t)blockIdx.y * NB + brow0 + tid] = rowsum[0][tid] + rowsum[1][tid];
}

// per-row: sum partials, lse = 64 + log(sum), loss_b = lse - tgt[b]
__global__ void row_lse_k(const float* __restrict__ partial, const float* __restrict__ tgt,
                          float* __restrict__ lossb, int nt) {
    int b = blockIdx.x;
    float s = 0.0f;
    for (int i = threadIdx.x; i < nt; i += 256)
        s += partial[(size_t)i * NB + b];
    s = wave_sum(s);
    __shared__ float wsum[4];
    if ((threadIdx.x & 63) == 0) wsum[threadIdx.x >> 6] = s;
    __syncthreads();
    if (threadIdx.x == 0)
        lossb[b] = 64.0f + logf(wsum[0] + wsum[1] + wsum[2] + wsum[3]) - tgt[b];
}

__global__ void mean_k(const float* __restrict__ lossb, float* __restrict__ out) {
    float s = 0.0f;
    for (int i = threadIdx.x; i < NB; i += 256) s += lossb[i];
    s = wave_sum(s);
    __shared__ float wsum[4];
    if ((threadIdx.x & 63) == 0) wsum[threadIdx.x >> 6] = s;
    __syncthreads();
    if (threadIdx.x == 0)
        out[0] = (wsum[0] + wsum[1] + wsum[2] + wsum[3]) * (1.0f / (float)NB);
}

extern "C" void kernel_launch(void* const* d_in, const int* in_sizes, int n_in,
                              void* d_out, int out_size, void* d_ws, size_t ws_size,
                              hipStream_t stream) {
    const float* x     = (const float*)d_in[0];
    const int*   label = (const int*)d_in[1];
    const float* w     = (const float*)d_in[2];
    float* out = (float*)d_out;
    char* ws = (char*)d_ws;

    // fast-path workspace layout (16B aligned)
    const size_t WQ_B   = (size_t)NC * ND;        // 51,200,000
    const size_t ISW_B  = 400000;                 // NC*4
    const size_t XQ_B   = (size_t)NB * ND;        // 524,288
    const size_t ISX_B  = 4096;
    const size_t PART2  = (size_t)NCT2 * NB * 4;  // 1,601,536
    const size_t FAST_REQ = WQ_B + ISW_B + XQ_B + ISX_B + PART2 + 8192;

    if (ws_size >= FAST_REQ) {
        unsigned char* wq      = (unsigned char*)(ws);
        float*         iswv    = (float*)(ws + WQ_B);
        unsigned char* xq      = (unsigned char*)(ws + WQ_B + ISW_B);
        float*         isxv    = (float*)(ws + WQ_B + ISW_B + XQ_B);
        float*         partial = (float*)(ws + WQ_B + ISW_B + XQ_B + ISX_B);
        float*         tgt     = (float*)(ws + WQ_B + ISW_B + XQ_B + ISX_B + PART2);
        float*         lossb   = (float*)(ws + WQ_B + ISW_B + XQ_B + ISX_B + PART2 + 4096);

        norm_input_i8_k <<<NB / 4, 256, 0, stream>>>(x, xq, isxv);
        conv_weight_i8_k<<<NC / 4, 256, 0, stream>>>(w, wq, iswv);
        dim3 grid(4, NCT2);
        gemm_i8_k<<<grid, 512, 0, stream>>>(xq, wq, isxv, iswv, label, partial, tgt);
        row_lse_k<<<NB, 256, 0, stream>>>(partial, tgt, lossb, NCT2);
        mean_k<<<1, 256, 0, stream>>>(lossb, out);
    } else {
        float*          invw    = (float*)(ws);
        unsigned short* xn      = (unsigned short*)(ws + 400384);
        float*          partial = (float*)(ws + 400384 + 1048576);
        float*          tgt     = (float*)(ws + 400384 + 1048576 + 3203072);
        float*          lossb   = (float*)(ws + 400384 + 1048576 + 3203072 + 4096);

        norm_input_k <<<NB / 4, 256, 0, stream>>>(x, xn);
        norm_weight_k<<<NC / 4, 256, 0, stream>>>(w, invw);
        dim3 grid(8, NCT);
        gemm_fb_k<<<grid, 256, 0, stream>>>(xn, w, invw, label, partial, tgt);
        row_lse_k<<<NB, 256, 0, stream>>>(partial, tgt, lossb, NCT);
        mean_k<<<1, 256, 0, stream>>>(lossb, out);
    }
}